// Round 7
// baseline (398.571 us; speedup 1.0000x reference)
//
#include <hip/hip_runtime.h>
#include <hip/hip_fp16.h>

// Problem constants
#define BB 16
#define HH 128
#define WW 128
#define CC 256
#define MM (BB*HH*WW)     // 262144

typedef __attribute__((ext_vector_type(8))) short s16x8;
typedef __attribute__((ext_vector_type(4))) float f32x4;

__device__ static inline unsigned short f2bf(float x) {
    union { float f; unsigned u; } v; v.f = x;
    unsigned r = v.u + 0x7fffu + ((v.u >> 16) & 1u);  // round-nearest-even
    return (unsigned short)(r >> 16);
}

// ---- W[512,256] f32 -> two k-grouped bf16 tables (x: k<256, y: k>=256)
// Wt[hy][g][n][j] : flat hy*65536 + (g*256+n)*8 + j,  k = hy*256 + g*8 + j
__global__ __launch_bounds__(256) void conv_w_kernel(const float* __restrict__ Wf,
                                                     unsigned short* __restrict__ Wt) {
    const int i = blockIdx.x * 256 + threadIdx.x;   // 0..131071 ; i = k*256+n
    const int n = i & 255, k = i >> 8;
    const int hy = k >> 8, g = (k >> 3) & 31, j = k & 7;
    Wt[hy * 65536 + ((size_t)(g * 256 + n) << 3) + j] = f2bf(Wf[i]);
}

// Scan 128 steps (running max) for one channel c into swizzled LDS tile.
// As halfword index (row w, channel c): w*256 + (((c>>3) ^ (w&7))<<3) + (c&7)
__device__ __forceinline__ void scan_to_lds(const float* __restrict__ src, size_t st,
                                            unsigned short* __restrict__ As, int c) {
    float b0,b1,b2,b3,b4,b5,b6,b7;
    const float* p = src;
    b0=p[0*st]; b1=p[1*st]; b2=p[2*st]; b3=p[3*st];
    b4=p[4*st]; b5=p[5*st]; b6=p[6*st]; b7=p[7*st];
    p += 8 * st;
    float run = -3.4e38f;
    const int chi = c >> 3, clo = c & 7;
#define CONSUME(v, wj)                                                     \
    do {                                                                   \
        run = fmaxf(run, (v));                                             \
        const int w_ = (wj);                                               \
        As[w_ * 256 + (((chi) ^ (w_ & 7)) << 3) + clo] = f2bf(run);        \
    } while (0)
    for (int g = 0; g < 16; ++g) {
        float n0,n1,n2,n3,n4,n5,n6,n7;
        const bool more = (g < 15);
        if (more) {
            n0=p[0*st]; n1=p[1*st]; n2=p[2*st]; n3=p[3*st];
            n4=p[4*st]; n5=p[5*st]; n6=p[6*st]; n7=p[7*st];
            p += 8 * st;
        }
        const int w0 = g * 8;
        CONSUME(b0,w0+0); CONSUME(b1,w0+1); CONSUME(b2,w0+2); CONSUME(b3,w0+3);
        CONSUME(b4,w0+4); CONSUME(b5,w0+5); CONSUME(b6,w0+6); CONSUME(b7,w0+7);
        if (more) { b0=n0; b1=n1; b2=n2; b3=n3; b4=n4; b5=n5; b6=n6; b7=n7; }
    }
#undef CONSUME
}

// Shared GEMM phase: C[128 x 256] = As(LDS, swizzled) @ Wv + ..., MFMA 16x16x32.
// 4 waves (wr = wid>>1 rows, wn = wid&1 cols), N in two halves (acc 64 VGPR).
// af row = wr*64+fm*16+(lane&15); logical chunk g = q*4+(lane>>4), phys = g^(row&7).
// Verified C/D layout: col = lane&15(+16fn), row = (lane>>4)*4 + r.

// ---- K1: h-scan + GEMM(Wy) -> partial f16. Block = (b,w), M-rows = h.
__global__ __launch_bounds__(256, 2) void hscan_gemm_kernel(const float* __restrict__ grid,
                                                            const unsigned short* __restrict__ Wt,
                                                            __half* __restrict__ partial) {
    __shared__ unsigned short As[32768];   // [128][256] bf16, swizzled
    const int t    = threadIdx.x;
    const int lane = t & 63;
    const int wid  = t >> 6;
    const int wr   = wid >> 1, wn = wid & 1;
    const int b    = blockIdx.x >> 7;
    const int w    = blockIdx.x & 127;

    scan_to_lds(grid + ((size_t)b * 16384 + w) * 256 + t, 32768, As, t);
    __syncthreads();

    const s16x8* Wv = (const s16x8*)(Wt + 65536);   // Wty (k = 256..511)
    #pragma unroll
    for (int nh = 0; nh < 2; ++nh) {
        f32x4 acc[4][4];
        #pragma unroll
        for (int i = 0; i < 4; ++i)
            #pragma unroll
            for (int j = 0; j < 4; ++j) acc[i][j] = (f32x4){0.f,0.f,0.f,0.f};
        #pragma unroll
        for (int q = 0; q < 8; ++q) {
            const int g = q * 4 + (lane >> 4);
            s16x8 af[4], bf[4];
            #pragma unroll
            for (int fm = 0; fm < 4; ++fm) {
                const int row = wr * 64 + fm * 16 + (lane & 15);
                af[fm] = *(const s16x8*)(As + row * 256 + ((g ^ (row & 7)) << 3));
            }
            #pragma unroll
            for (int fn = 0; fn < 4; ++fn) {
                const int n = nh * 128 + wn * 64 + fn * 16 + (lane & 15);
                bf[fn] = Wv[g * 256 + n];
            }
            #pragma unroll
            for (int fm = 0; fm < 4; ++fm)
                #pragma unroll
                for (int fn = 0; fn < 4; ++fn)
                    acc[fm][fn] = __builtin_amdgcn_mfma_f32_16x16x32_bf16(
                        af[fm], bf[fn], acc[fm][fn], 0, 0, 0);
        }
        // partial[((b*128+h)*128 + w)*256 + col] = f16(acc)
        #pragma unroll
        for (int fn = 0; fn < 4; ++fn) {
            const int col = nh * 128 + wn * 64 + fn * 16 + (lane & 15);
            #pragma unroll
            for (int fm = 0; fm < 4; ++fm) {
                const int rbase = wr * 64 + fm * 16 + ((lane >> 4) << 2);
                #pragma unroll
                for (int r = 0; r < 4; ++r) {
                    const int h = rbase + r;
                    partial[(((size_t)b * 128 + h) * 128 + w) * 256 + col] =
                        __float2half(acc[fm][fn][r]);
                }
            }
        }
    }
}

// ---- K2: w-scan + GEMM(Wx) + partial + bias -> out f32. Block = (b,h), M-rows = w.
__global__ __launch_bounds__(256, 2) void wscan_gemm_kernel(const float* __restrict__ grid,
                                                            const unsigned short* __restrict__ Wt,
                                                            const __half* __restrict__ partial,
                                                            const float* __restrict__ bias,
                                                            float* __restrict__ out) {
    __shared__ unsigned short As[32768];
    const int t    = threadIdx.x;
    const int lane = t & 63;
    const int wid  = t >> 6;
    const int wr   = wid >> 1, wn = wid & 1;
    const size_t bh = blockIdx.x;       // b*128 + h

    scan_to_lds(grid + bh * 32768 + t, 256, As, t);
    __syncthreads();

    const s16x8* Wv = (const s16x8*)Wt;             // Wtx (k = 0..255)
    #pragma unroll
    for (int nh = 0; nh < 2; ++nh) {
        f32x4 acc[4][4];
        #pragma unroll
        for (int i = 0; i < 4; ++i)
            #pragma unroll
            for (int j = 0; j < 4; ++j) acc[i][j] = (f32x4){0.f,0.f,0.f,0.f};
        #pragma unroll
        for (int q = 0; q < 8; ++q) {
            const int g = q * 4 + (lane >> 4);
            s16x8 af[4], bf[4];
            #pragma unroll
            for (int fm = 0; fm < 4; ++fm) {
                const int row = wr * 64 + fm * 16 + (lane & 15);
                af[fm] = *(const s16x8*)(As + row * 256 + ((g ^ (row & 7)) << 3));
            }
            #pragma unroll
            for (int fn = 0; fn < 4; ++fn) {
                const int n = nh * 128 + wn * 64 + fn * 16 + (lane & 15);
                bf[fn] = Wv[g * 256 + n];
            }
            #pragma unroll
            for (int fm = 0; fm < 4; ++fm)
                #pragma unroll
                for (int fn = 0; fn < 4; ++fn)
                    acc[fm][fn] = __builtin_amdgcn_mfma_f32_16x16x32_bf16(
                        af[fm], bf[fn], acc[fm][fn], 0, 0, 0);
        }
        // out[(bh*128 + w)*256 + col] = acc + partial + bias
        #pragma unroll
        for (int fn = 0; fn < 4; ++fn) {
            const int col = nh * 128 + wn * 64 + fn * 16 + (lane & 15);
            const float bb = bias[col];
            #pragma unroll
            for (int fm = 0; fm < 4; ++fm) {
                const int rbase = wr * 64 + fm * 16 + ((lane >> 4) << 2);
                #pragma unroll
                for (int r = 0; r < 4; ++r) {
                    const size_t idx = (bh * 128 + (rbase + r)) * 256 + col;
                    out[idx] = acc[fm][fn][r] + __half2float(partial[idx]) + bb;
                }
            }
        }
    }
}

extern "C" void kernel_launch(void* const* d_in, const int* in_sizes, int n_in,
                              void* d_out, int out_size, void* d_ws, size_t ws_size,
                              hipStream_t stream) {
    const float* grid = (const float*)d_in[0];
    const float* Wf   = (const float*)d_in[1];
    const float* bias = (const float*)d_in[2];
    float* out        = (float*)d_out;

    // workspace: partial f16 [M,256] = 128 MB, then Wt (2 tables) 256 KB
    __half* partial    = (__half*)d_ws;
    unsigned short* Wt = (unsigned short*)((char*)d_ws + (size_t)134217728);

    conv_w_kernel<<<512, 256, 0, stream>>>(Wf, Wt);
    hscan_gemm_kernel<<<2048, 256, 0, stream>>>(grid, Wt, partial);
    wscan_gemm_kernel<<<2048, 256, 0, stream>>>(grid, Wt, partial, bias, out);
}

// Round 8
// 268.870 us; speedup vs baseline: 1.4824x; 1.4824x over previous
//
#include <hip/hip_runtime.h>
#include <hip/hip_fp16.h>

#define BB 16
#define HH 128
#define WW 128
#define CC 256

typedef __attribute__((ext_vector_type(8))) short s16x8;
typedef __attribute__((ext_vector_type(8))) unsigned short u16x8;
typedef __attribute__((ext_vector_type(4))) float f32x4;
typedef __attribute__((ext_vector_type(4))) int i32x4;

__device__ static inline unsigned short f2bf(float x) {
    union { float f; unsigned u; } v; v.f = x;
    unsigned r = v.u + 0x7fffu + ((v.u >> 16) & 1u);  // RNE
    return (unsigned short)(r >> 16);
}
__device__ static inline float bf2f(unsigned short u) {
    union { unsigned u; float f; } v; v.u = (unsigned)u << 16; return v.f;
}
__device__ static inline unsigned short h2u(__half h) {
    unsigned short u; __builtin_memcpy(&u, &h, 2); return u;
}
__device__ static inline float u2f16(unsigned short u) {
    __half h; __builtin_memcpy(&h, &u, 2); return __half2float(h);
}
// swizzled halfword index into a [128 row][256 col] LDS tile
__device__ static inline int sidx(int row, int col) {
    return row * 256 + (((col >> 3) ^ (row & 7)) << 3) + (col & 7);
}

// ---- W[512,256] f32 -> two k-grouped bf16 tables (x: k<256, y: k>=256)
// Wt[hy][g][n][j] : flat hy*65536 + (g*256+n)*8 + j,  k = hy*256 + g*8 + j
__global__ __launch_bounds__(256) void conv_w_kernel(const float* __restrict__ Wf,
                                                     unsigned short* __restrict__ Wt) {
    const int i = blockIdx.x * 256 + threadIdx.x;   // i = k*256+n
    const int n = i & 255, k = i >> 8;
    const int hy = k >> 8, g = (k >> 3) & 31, j = k & 7;
    Wt[hy * 65536 + ((size_t)(g * 256 + n) << 3) + j] = f2bf(Wf[i]);
}

// ---- scan 64 rows (running max) for channel c into swizzled LDS bf16 tile
__device__ __forceinline__ void scan_half(const float* __restrict__ src, size_t st,
                                          unsigned short* __restrict__ As, int c, int row0) {
    float buf[8], nxt[8];
    const float* p = src;
    #pragma unroll
    for (int j = 0; j < 8; ++j) buf[j] = p[(size_t)j * st];
    __builtin_amdgcn_sched_group_barrier(0x20, 8, 0);
    p += 8 * st;
    float run = -3.4e38f;
    const int chi = c >> 3, clo = c & 7;
    #pragma unroll
    for (int g = 0; g < 8; ++g) {
        if (g < 7) {
            #pragma unroll
            for (int j = 0; j < 8; ++j) nxt[j] = p[(size_t)j * st];
            __builtin_amdgcn_sched_group_barrier(0x20, 8, 0);
            p += 8 * st;
        }
        #pragma unroll
        for (int j = 0; j < 8; ++j) {
            run = fmaxf(run, buf[j]);
            const int row = row0 + g * 8 + j;
            As[row * 256 + ((chi ^ (row & 7)) << 3) + clo] = f2bf(run);
        }
        if (g < 7) {
            #pragma unroll
            for (int j = 0; j < 8; ++j) buf[j] = nxt[j];
        }
    }
}

// ---- carry fix: rows 64..127 get fmax'd with As[63][c] (s=1 threads only)
__device__ __forceinline__ void carry_fix(unsigned short* __restrict__ As, int c) {
    const unsigned short cb = As[sidx(63, c)];
    const float cf = bf2f(cb);
    #pragma unroll 8
    for (int j = 0; j < 64; ++j) {
        const int ix = sidx(64 + j, c);
        const unsigned short v = As[ix];
        As[ix] = (bf2f(v) >= cf) ? v : cb;
    }
}

// ---- GEMM C[128x256] = As(bf16,swz) @ Wv, then stage C as f16 back into As.
// 8 waves: wr = wid>>2 (2 row-tiles of 64), wn = wid&3 (4 col-tiles of 64).
__device__ __forceinline__ void gemm_stage(unsigned short* __restrict__ As,
                                           const s16x8* __restrict__ Wv, int t) {
    const int lane = t & 63, wid = t >> 6;
    const int wr = wid >> 2, wn = wid & 3;
    f32x4 acc[4][4];
    #pragma unroll
    for (int i = 0; i < 4; ++i)
        #pragma unroll
        for (int j = 0; j < 4; ++j) acc[i][j] = (f32x4){0.f, 0.f, 0.f, 0.f};

    #pragma unroll
    for (int q = 0; q < 8; ++q) {
        const int g = q * 4 + (lane >> 4);     // 16B chunk index, K=256 -> g in 0..31
        s16x8 af[4], bf[4];
        #pragma unroll
        for (int fm = 0; fm < 4; ++fm) {
            const int row = wr * 64 + fm * 16 + (lane & 15);
            af[fm] = *(const s16x8*)(As + row * 256 + ((g ^ (row & 7)) << 3));
        }
        #pragma unroll
        for (int fn = 0; fn < 4; ++fn)
            bf[fn] = Wv[g * 256 + wn * 64 + fn * 16 + (lane & 15)];
        #pragma unroll
        for (int fm = 0; fm < 4; ++fm)
            #pragma unroll
            for (int fn = 0; fn < 4; ++fn)
                acc[fm][fn] = __builtin_amdgcn_mfma_f32_16x16x32_bf16(
                    af[fm], bf[fn], acc[fm][fn], 0, 0, 0);
    }
    __syncthreads();   // all As reads done before overwrite
    // stage acc as f16 into As (swizzled). C/D: col=lane&15, row=(lane>>4)*4+r.
    #pragma unroll
    for (int fn = 0; fn < 4; ++fn) {
        const int col = wn * 64 + fn * 16 + (lane & 15);
        #pragma unroll
        for (int fm = 0; fm < 4; ++fm) {
            const int rbase = wr * 64 + fm * 16 + ((lane >> 4) << 2);
            #pragma unroll
            for (int r = 0; r < 4; ++r)
                As[sidx(rbase + r, col)] = h2u(__float2half(acc[fm][fn][r]));
        }
    }
    __syncthreads();
}

// ---- K1: h-scan + GEMM(Wy) -> partial f16 (layout b,h,w,c). Block = (b,w).
__global__ __launch_bounds__(512, 3) void hscan_gemm_kernel(const float* __restrict__ grid,
                                                            const unsigned short* __restrict__ Wt,
                                                            unsigned short* __restrict__ partial) {
    __shared__ unsigned short As[32768];   // [128][256], swizzled
    const int t = threadIdx.x;
    const int c = t & 255, s = t >> 8;
    const int b = blockIdx.x >> 7;
    const int w = blockIdx.x & 127;

    // rows = h; addr = ((b*128 + h)*128 + w)*256 + c, stride_h = 32768 floats
    const float* base = grid + ((size_t)(b * 128 + s * 64) * 128 + w) * 256 + c;
    scan_half(base, 32768, As, c, s * 64);
    __syncthreads();
    if (s == 1) carry_fix(As, c);
    __syncthreads();

    gemm_stage(As, (const s16x8*)(Wt + 65536), t);   // Wy table

    // drain: partial[((b*128+h)*128 + w)*256 + col], 16B/lane
    #pragma unroll
    for (int it = 0; it < 8; ++it) {
        const int f = it * 4096 + t * 8;
        const int row = f >> 8, col = f & 255;     // row = h
        const i32x4 v = *(const i32x4*)(As + sidx(row, col));
        *(i32x4*)(partial + (((size_t)b * 128 + row) * 128 + w) * 256 + col) = v;
    }
}

// ---- K2: w-scan + GEMM(Wx) + partial + bias -> out f32. Block = (b,h).
__global__ __launch_bounds__(512, 3) void wscan_gemm_kernel(const float* __restrict__ grid,
                                                            const unsigned short* __restrict__ Wt,
                                                            const unsigned short* __restrict__ partial,
                                                            const float* __restrict__ bias,
                                                            float* __restrict__ out) {
    __shared__ unsigned short As[32768];
    const int t = threadIdx.x;
    const int c = t & 255, s = t >> 8;
    const size_t bh = blockIdx.x;       // b*128 + h

    // rows = w; addr = (bh*128 + w)*256 + c, stride_w = 256 floats
    const float* base = grid + (bh * 128 + (size_t)(s * 64)) * 256 + c;
    scan_half(base, 256, As, c, s * 64);
    __syncthreads();
    if (s == 1) carry_fix(As, c);
    __syncthreads();

    gemm_stage(As, (const s16x8*)Wt, t);             // Wx table

    // drain: out = lds_f16 + partial_f16 + bias, fully coalesced
    const int colf = (t * 8) & 255;
    float bv[8];
    #pragma unroll
    for (int k = 0; k < 8; ++k) bv[k] = bias[colf + k];

    #pragma unroll
    for (int it = 0; it < 8; ++it) {
        const int f = it * 4096 + t * 8;
        const int row = f >> 8, col = f & 255;      // row = w
        const u16x8 lv = *(const u16x8*)(As + sidx(row, col));
        const size_t gi = (bh * 128 + row) * 256 + col;
        const u16x8 pv = *(const u16x8*)(partial + gi);
        f32x4 o0, o1;
        #pragma unroll
        for (int k = 0; k < 4; ++k)
            o0[k] = u2f16((unsigned short)lv[k]) + u2f16((unsigned short)pv[k]) + bv[k];
        #pragma unroll
        for (int k = 0; k < 4; ++k)
            o1[k] = u2f16((unsigned short)lv[4 + k]) + u2f16((unsigned short)pv[4 + k]) + bv[4 + k];
        *(f32x4*)(out + gi)     = o0;
        *(f32x4*)(out + gi + 4) = o1;
    }
}

extern "C" void kernel_launch(void* const* d_in, const int* in_sizes, int n_in,
                              void* d_out, int out_size, void* d_ws, size_t ws_size,
                              hipStream_t stream) {
    const float* grid = (const float*)d_in[0];
    const float* Wf   = (const float*)d_in[1];
    const float* bias = (const float*)d_in[2];
    float* out        = (float*)d_out;

    // workspace: partial f16 [M,256] = 128 MB, then Wt (2 tables) 256 KB
    unsigned short* partial = (unsigned short*)d_ws;
    unsigned short* Wt      = (unsigned short*)((char*)d_ws + (size_t)134217728);

    conv_w_kernel<<<512, 256, 0, stream>>>(Wf, Wt);
    hscan_gemm_kernel<<<2048, 512, 0, stream>>>(grid, Wt, partial);
    wscan_gemm_kernel<<<2048, 512, 0, stream>>>(grid, Wt, partial, bias, out);
}

// Round 9
// 257.832 us; speedup vs baseline: 1.5459x; 1.0428x over previous
//
#include <hip/hip_runtime.h>
#include <hip/hip_fp16.h>

#define BB 16
#define HH 128
#define WW 128
#define CC 256

typedef __attribute__((ext_vector_type(8))) short s16x8;
typedef __attribute__((ext_vector_type(8))) unsigned short u16x8;
typedef __attribute__((ext_vector_type(4))) float f32x4;
typedef __attribute__((ext_vector_type(4))) int i32x4;

__device__ static inline unsigned short f2bf(float x) {
    union { float f; unsigned u; } v; v.f = x;
    unsigned r = v.u + 0x7fffu + ((v.u >> 16) & 1u);  // RNE
    return (unsigned short)(r >> 16);
}
__device__ static inline float bf2f(unsigned short u) {
    union { unsigned u; float f; } v; v.u = (unsigned)u << 16; return v.f;
}
__device__ static inline unsigned short h2u(__half h) {
    unsigned short u; __builtin_memcpy(&u, &h, 2); return u;
}
__device__ static inline float u2f16(unsigned short u) {
    __half h; __builtin_memcpy(&h, &u, 2); return __half2float(h);
}
// swizzled halfword index into [128 row][256 col] LDS tile (16B-chunk XOR)
__device__ static inline int sidx(int row, int col) {
    return row * 256 + (((col >> 3) ^ (row & 7)) << 3) + (col & 7);
}
// same, 8B granularity: c4 covers cols c4*4 .. c4*4+3
__device__ static inline int sidx4(int row, int c4) {
    return row * 256 + (((c4 >> 1) ^ (row & 7)) << 3) + (c4 & 1) * 4;
}

// ---- W[512,256] f32 -> two k-grouped bf16 tables (x: k<256, y: k>=256)
__global__ __launch_bounds__(256) void conv_w_kernel(const float* __restrict__ Wf,
                                                     unsigned short* __restrict__ Wt) {
    const int i = blockIdx.x * 256 + threadIdx.x;   // i = k*256+n
    const int n = i & 255, k = i >> 8;
    const int hy = k >> 8, g = (k >> 3) & 31, j = k & 7;
    Wt[hy * 65536 + ((size_t)(g * 256 + n) << 3) + j] = f2bf(Wf[i]);
}

// ---- scan 16 rows (seg s) of 4 channels (c4) into swizzled LDS; seg-max out.
// st = row stride in float4 units. base points at (row s*16, col c4*4).
__device__ __forceinline__ void scan16_to_lds(const float4* __restrict__ base, size_t st,
                                              unsigned short* __restrict__ As,
                                              unsigned short* __restrict__ smax,
                                              int c4, int s) {
    const int row0 = s * 16;
    float4 buf[8], nxt[8];
    #pragma unroll
    for (int j = 0; j < 8; ++j) buf[j] = base[(size_t)j * st];
    __builtin_amdgcn_sched_group_barrier(0x20, 8, 0);
    #pragma unroll
    for (int j = 0; j < 8; ++j) nxt[j] = base[(size_t)(8 + j) * st];
    __builtin_amdgcn_sched_group_barrier(0x20, 8, 0);
    float4 run = make_float4(-3.4e38f, -3.4e38f, -3.4e38f, -3.4e38f);
    #pragma unroll
    for (int j = 0; j < 8; ++j) {
        run.x = fmaxf(run.x, buf[j].x); run.y = fmaxf(run.y, buf[j].y);
        run.z = fmaxf(run.z, buf[j].z); run.w = fmaxf(run.w, buf[j].w);
        ushort4 o; o.x = f2bf(run.x); o.y = f2bf(run.y); o.z = f2bf(run.z); o.w = f2bf(run.w);
        *(ushort4*)(As + sidx4(row0 + j, c4)) = o;
    }
    #pragma unroll
    for (int j = 0; j < 8; ++j) {
        run.x = fmaxf(run.x, nxt[j].x); run.y = fmaxf(run.y, nxt[j].y);
        run.z = fmaxf(run.z, nxt[j].z); run.w = fmaxf(run.w, nxt[j].w);
        ushort4 o; o.x = f2bf(run.x); o.y = f2bf(run.y); o.z = f2bf(run.z); o.w = f2bf(run.w);
        *(ushort4*)(As + sidx4(row0 + 8 + j, c4)) = o;
    }
    ushort4 sm; sm.x = f2bf(run.x); sm.y = f2bf(run.y); sm.z = f2bf(run.z); sm.w = f2bf(run.w);
    *(ushort4*)(smax + s * 256 + c4 * 4) = sm;
}

// ---- apply prefix carry (seg-maxes 0..s-1) to this thread's 16 rows
__device__ __forceinline__ void carry_apply(unsigned short* __restrict__ As,
                                            const unsigned short* __restrict__ smax,
                                            int c4, int s) {
    if (s == 0) return;   // s is wave-uniform -> no divergence
    float4 cf = make_float4(-3.4e38f, -3.4e38f, -3.4e38f, -3.4e38f);
    for (int k = 0; k < s; ++k) {
        const ushort4 m = *(const ushort4*)(smax + k * 256 + c4 * 4);
        cf.x = fmaxf(cf.x, bf2f(m.x)); cf.y = fmaxf(cf.y, bf2f(m.y));
        cf.z = fmaxf(cf.z, bf2f(m.z)); cf.w = fmaxf(cf.w, bf2f(m.w));
    }
    ushort4 cb; cb.x = f2bf(cf.x); cb.y = f2bf(cf.y); cb.z = f2bf(cf.z); cb.w = f2bf(cf.w);
    const int row0 = s * 16;
    #pragma unroll
    for (int r = 0; r < 16; ++r) {
        unsigned short* pp = As + sidx4(row0 + r, c4);
        ushort4 v = *(ushort4*)(pp);
        ushort4 o;
        o.x = (bf2f(v.x) >= cf.x) ? v.x : cb.x;
        o.y = (bf2f(v.y) >= cf.y) ? v.y : cb.y;
        o.z = (bf2f(v.z) >= cf.z) ? v.z : cb.z;
        o.w = (bf2f(v.w) >= cf.w) ? v.w : cb.w;
        *(ushort4*)(pp) = o;
    }
}

// ---- GEMM C[128x256] = As(bf16,swz) @ Wv, stage C as f16 back into As.
// 8 waves: wr = wid>>2 (2 row-tiles of 64), wn = wid&3 (4 col-tiles of 64).
__device__ __forceinline__ void gemm_stage(unsigned short* __restrict__ As,
                                           const s16x8* __restrict__ Wv, int t) {
    const int lane = t & 63, wid = t >> 6;
    const int wr = wid >> 2, wn = wid & 3;
    f32x4 acc[4][4];
    #pragma unroll
    for (int i = 0; i < 4; ++i)
        #pragma unroll
        for (int j = 0; j < 4; ++j) acc[i][j] = (f32x4){0.f, 0.f, 0.f, 0.f};

    #pragma unroll
    for (int q = 0; q < 8; ++q) {
        const int g = q * 4 + (lane >> 4);     // 16B chunk index, 0..31
        s16x8 af[4], bf[4];
        #pragma unroll
        for (int fm = 0; fm < 4; ++fm) {
            const int row = wr * 64 + fm * 16 + (lane & 15);
            af[fm] = *(const s16x8*)(As + row * 256 + ((g ^ (row & 7)) << 3));
        }
        #pragma unroll
        for (int fn = 0; fn < 4; ++fn)
            bf[fn] = Wv[g * 256 + wn * 64 + fn * 16 + (lane & 15)];
        #pragma unroll
        for (int fm = 0; fm < 4; ++fm)
            #pragma unroll
            for (int fn = 0; fn < 4; ++fn)
                acc[fm][fn] = __builtin_amdgcn_mfma_f32_16x16x32_bf16(
                    af[fm], bf[fn], acc[fm][fn], 0, 0, 0);
    }
    __syncthreads();   // all As reads done before overwrite
    #pragma unroll
    for (int fn = 0; fn < 4; ++fn) {
        const int col = wn * 64 + fn * 16 + (lane & 15);
        #pragma unroll
        for (int fm = 0; fm < 4; ++fm) {
            const int rbase = wr * 64 + fm * 16 + ((lane >> 4) << 2);
            #pragma unroll
            for (int r = 0; r < 4; ++r)
                As[sidx(rbase + r, col)] = h2u(__float2half(acc[fm][fn][r]));
        }
    }
    __syncthreads();
}

// ---- K1: h-scan + GEMM(Wy) -> partial f16 (layout b,h,w,c). Block = (b,w).
__global__ __launch_bounds__(512, 4) void hscan_gemm_kernel(const float* __restrict__ grid,
                                                            const unsigned short* __restrict__ Wt,
                                                            unsigned short* __restrict__ partial) {
    __shared__ unsigned short As[32768];   // [128][256] bf16, swizzled
    __shared__ unsigned short smax[2048];  // [8 seg][256 c]
    const int t = threadIdx.x;
    const int c4 = t & 63, s = t >> 6;
    const int b = blockIdx.x >> 7;
    const int w = blockIdx.x & 127;

    // rows = h; float4 row stride = 128*256/4 = 8192
    const float4* base = (const float4*)(grid + ((size_t)(b * 128 + s * 16) * 128 + w) * 256) + c4;
    scan16_to_lds(base, 8192, As, smax, c4, s);
    __syncthreads();
    carry_apply(As, smax, c4, s);
    __syncthreads();

    gemm_stage(As, (const s16x8*)(Wt + 65536), t);   // Wy table

    // drain: partial[((b*128+h)*128 + w)*256 + col], 16B/lane
    #pragma unroll
    for (int it = 0; it < 8; ++it) {
        const int f = it * 4096 + t * 8;
        const int row = f >> 8, col = f & 255;     // row = h
        const i32x4 v = *(const i32x4*)(As + sidx(row, col));
        *(i32x4*)(partial + (((size_t)b * 128 + row) * 128 + w) * 256 + col) = v;
    }
}

// ---- K2: w-scan + GEMM(Wx) + partial + bias -> out f32. Block = (b,h).
__global__ __launch_bounds__(512, 4) void wscan_gemm_kernel(const float* __restrict__ grid,
                                                            const unsigned short* __restrict__ Wt,
                                                            const unsigned short* __restrict__ partial,
                                                            const float* __restrict__ bias,
                                                            float* __restrict__ out) {
    __shared__ unsigned short As[32768];
    __shared__ unsigned short smax[2048];
    const int t = threadIdx.x;
    const int c4 = t & 63, s = t >> 6;
    const size_t bh = blockIdx.x;       // b*128 + h

    // rows = w; float4 row stride = 256/4 = 64
    const float4* base = (const float4*)(grid + (bh * 128 + (size_t)(s * 16)) * 256) + c4;
    scan16_to_lds(base, 64, As, smax, c4, s);
    __syncthreads();
    carry_apply(As, smax, c4, s);
    __syncthreads();

    gemm_stage(As, (const s16x8*)Wt, t);             // Wx table

    // drain: out = lds_f16 + partial_f16 + bias, fully coalesced
    const int colf = (t * 8) & 255;
    float bv[8];
    #pragma unroll
    for (int k = 0; k < 8; ++k) bv[k] = bias[colf + k];

    #pragma unroll
    for (int it = 0; it < 8; ++it) {
        const int f = it * 4096 + t * 8;
        const int row = f >> 8, col = f & 255;      // row = w
        const u16x8 lv = *(const u16x8*)(As + sidx(row, col));
        const size_t gi = (bh * 128 + row) * 256 + col;
        const u16x8 pv = *(const u16x8*)(partial + gi);
        f32x4 o0, o1;
        #pragma unroll
        for (int k = 0; k < 4; ++k)
            o0[k] = u2f16((unsigned short)lv[k]) + u2f16((unsigned short)pv[k]) + bv[k];
        #pragma unroll
        for (int k = 0; k < 4; ++k)
            o1[k] = u2f16((unsigned short)lv[4 + k]) + u2f16((unsigned short)pv[4 + k]) + bv[4 + k];
        *(f32x4*)(out + gi)     = o0;
        *(f32x4*)(out + gi + 4) = o1;
    }
}

extern "C" void kernel_launch(void* const* d_in, const int* in_sizes, int n_in,
                              void* d_out, int out_size, void* d_ws, size_t ws_size,
                              hipStream_t stream) {
    const float* grid = (const float*)d_in[0];
    const float* Wf   = (const float*)d_in[1];
    const float* bias = (const float*)d_in[2];
    float* out        = (float*)d_out;

    // workspace: partial f16 [M,256] = 128 MB, then Wt (2 tables) 256 KB
    unsigned short* partial = (unsigned short*)d_ws;
    unsigned short* Wt      = (unsigned short*)((char*)d_ws + (size_t)134217728);

    conv_w_kernel<<<512, 256, 0, stream>>>(Wf, Wt);
    hscan_gemm_kernel<<<2048, 512, 0, stream>>>(grid, Wt, partial);
    wscan_gemm_kernel<<<2048, 512, 0, stream>>>(grid, Wt, partial, bias, out);
}